// Round 17
// baseline (389.762 us; speedup 1.0000x reference)
//
#include <hip/hip_runtime.h>
#include <math.h>

#define NN 50000
#define EE 1000000
#define BB 512

typedef _Float16 hf;
typedef __attribute__((ext_vector_type(2))) _Float16 hf2;

__device__ __forceinline__ float sigmoidf_(float x) { return 1.0f / (1.0f + __expf(-x)); }

__device__ __forceinline__ int uloadi(const int* p) {
    return __builtin_amdgcn_readfirstlane(*p);
}
__device__ __forceinline__ unsigned uloadu(const unsigned* p) {
    return (unsigned)__builtin_amdgcn_readfirstlane((int)*p);
}

// f32 pair -> packed half2 (as uint)
__device__ __forceinline__ unsigned pack2(float a, float b) {
    hf2 h; h.x = (_Float16)a; h.y = (_Float16)b;
    return __builtin_bit_cast(unsigned, h);
}

// acc += a(2xf16) . w(2xf16), f32 accumulate
__device__ __forceinline__ float dot2acc(unsigned au, hf2 w, float acc) {
    hf2 a = __builtin_bit_cast(hf2, au);
#if __has_builtin(__builtin_amdgcn_fdot2)
    return __builtin_amdgcn_fdot2(a, w, acc, false);
#else
    return acc + (float)a.x * (float)w.x + (float)a.y * (float)w.y;
#endif
}

// ---------------------------------------------------------------------------
// Fused setup: zero counts + graph bounds + LSTM transpose + x -> fp16.
// ---------------------------------------------------------------------------
__global__ __launch_bounds__(256) void setup_kernel(
    const int* __restrict__ batch, int* __restrict__ brow,
    const float* __restrict__ wih, const float* __restrict__ whh,
    float* __restrict__ wihT, float* __restrict__ whhT,
    int* __restrict__ counts, const float* __restrict__ x, unsigned* __restrict__ xh)
{
    int i = blockIdx.x * 256 + threadIdx.x;
    if (i < NN) {
        counts[i] = 0;
        int bi = batch[i];
        int prev = (i == 0) ? -1 : batch[i - 1];
        for (int v = prev + 1; v <= bi; ++v) brow[v] = i;
        if (i == NN - 1) for (int v = bi + 1; v <= BB; ++v) brow[v] = NN;
    }
    if (i < 128 * 256) wihT[i] = wih[(i & 255) * 128 + (i >> 8)];
    if (i < 64 * 256)  whhT[i] = whh[(i & 255) * 64 + (i >> 8)];
    if (i < NN * 8) {
        float4 v = reinterpret_cast<const float4*>(x)[i];
        uint2 o; o.x = pack2(v.x, v.y); o.y = pack2(v.z, v.w);
        reinterpret_cast<uint2*>(xh)[i] = o;
    }
}

// ---------------------------------------------------------------------------
// CSR build, single atomic pass: rank -> scan -> pack (atomic-free).
// ---------------------------------------------------------------------------
__global__ __launch_bounds__(256) void rank_kernel(const int* __restrict__ ei,
                                                   int* __restrict__ counts,
                                                   int* __restrict__ rnk)
{
    int e = blockIdx.x * 256 + threadIdx.x;
    if (e < EE) rnk[e] = atomicAdd(&counts[ei[EE + e]], 1);
}

__global__ __launch_bounds__(1024) void scan_kernel(const int* __restrict__ counts,
                                                    int* __restrict__ rowptr)
{
    __shared__ int s[1024];
    int t = threadIdx.x;
    const int CH = (NN + 1023) / 1024;
    int lo = t * CH, hi = lo + CH < NN ? lo + CH : NN;
    int sum = 0;
    for (int i = lo; i < hi; ++i) sum += counts[i];
    s[t] = sum;
    __syncthreads();
    for (int off = 1; off < 1024; off <<= 1) {
        int v = (t >= off) ? s[t - off] : 0;
        __syncthreads();
        s[t] += v;
        __syncthreads();
    }
    int base = (t > 0) ? s[t - 1] : 0;
    for (int i = lo; i < hi; ++i) { rowptr[i] = base; base += counts[i]; }
    if (t == 1023) rowptr[NN] = s[1023];
}

__global__ __launch_bounds__(256) void pack_kernel(
    const int* __restrict__ ei, const int* __restrict__ rnk,
    const int* __restrict__ rowptr,
    const float* __restrict__ eattr, const float* __restrict__ efeat,
    int* __restrict__ srcp, unsigned* __restrict__ eah)
{
    int e = blockIdx.x * 256 + threadIdx.x;
    if (e >= EE) return;
    int pos = rowptr[ei[EE + e]] + rnk[e];
    srcp[pos] = ei[e];
    const float4* pa = reinterpret_cast<const float4*>(eattr) + (size_t)e * 2;
    const float4* pf = reinterpret_cast<const float4*>(efeat) + (size_t)e * 2;
    float4 v0 = pa[0], v1 = pa[1], v2 = pf[0], v3 = pf[1];
    uint4 o0, o1;
    o0.x = pack2(v0.x, v0.y); o0.y = pack2(v0.z, v0.w);
    o0.z = pack2(v1.x, v1.y); o0.w = pack2(v1.z, v1.w);
    o1.x = pack2(v2.x, v2.y); o1.y = pack2(v2.z, v2.w);
    o1.z = pack2(v3.x, v3.y); o1.w = pack2(v3.z, v3.w);
    uint4* o = reinterpret_cast<uint4*>(eah + (size_t)pos * 8);
    o[0] = o0; o[1] = o1;
}

// ---------------------------------------------------------------------------
// gine32: one wave/node, one edge per half-wave, 4-edge groups (R16-proven).
// ---------------------------------------------------------------------------
__global__ __launch_bounds__(256) void gine32_kernel(
    const hf* __restrict__ xin, const int* __restrict__ pidx,
    const int* __restrict__ rowptr, const unsigned* __restrict__ eah,
    const float* __restrict__ ew, const float* __restrict__ eb,
    const float* __restrict__ w1, const float* __restrict__ b1,
    const float* __restrict__ w2, const float* __restrict__ b2,
    hf* __restrict__ hout)
{
    __shared__ float w1_lds[32 * 64];
    for (int i = threadIdx.x; i < 32 * 64; i += 256) w1_lds[i] = w1[i];
    __syncthreads();

    int wave = threadIdx.x >> 6, lane = threadIdx.x & 63;
    int node = blockIdx.x * 4 + wave;
    if (node >= NN) return;

    int ch = lane & 31;
    int half = lane >> 5;

    hf2 wh[8];
#pragma unroll
    for (int k = 0; k < 8; ++k) {
        wh[k].x = (_Float16)ew[(2 * k) * 32 + ch];
        wh[k].y = (_Float16)ew[(2 * k + 1) * 32 + ch];
    }
    float ebv = eb[ch];

    int start = rowptr[node], end = rowptr[node + 1];
    float agg = 0.0f;

    int j = start;
    for (; j + 3 < end; j += 4) {      // 4 edges: 2 gather instrs (half-wave each)
        int jb = __builtin_amdgcn_readfirstlane(j);
        int s0 = uloadi(pidx + jb),     s1 = uloadi(pidx + jb + 1);
        int s2 = uloadi(pidx + jb + 2), s3 = uloadi(pidx + jb + 3);
        float xva = (float)xin[(size_t)(half ? s1 : s0) * 32 + ch];
        float xvb = (float)xin[(size_t)(half ? s3 : s2) * 32 + ch];
        const unsigned* p = eah + (size_t)jb * 8;
        unsigned a0[8], a1[8], a2[8], a3[8];
#pragma unroll
        for (int k = 0; k < 8; ++k) {
            a0[k] = uloadu(p + k);
            a1[k] = uloadu(p + 8 + k);
            a2[k] = uloadu(p + 16 + k);
            a3[k] = uloadu(p + 24 + k);
        }
        float m0 = 0.0f, m1 = 0.0f, m2 = 0.0f, m3 = 0.0f;
#pragma unroll
        for (int k = 0; k < 8; ++k) {
            m0 = dot2acc(a0[k], wh[k], m0);
            m1 = dot2acc(a1[k], wh[k], m1);
            m2 = dot2acc(a2[k], wh[k], m2);
            m3 = dot2acc(a3[k], wh[k], m3);
        }
        agg += fmaxf(xva + (half ? m1 : m0) + ebv, 0.0f)
             + fmaxf(xvb + (half ? m3 : m2) + ebv, 0.0f);
    }
    for (; j + 1 < end; j += 2) {      // 2-edge remainder
        int jb = __builtin_amdgcn_readfirstlane(j);
        int s0 = uloadi(pidx + jb);
        int s1 = uloadi(pidx + jb + 1);
        float xv = (float)xin[(size_t)(half ? s1 : s0) * 32 + ch];
        const unsigned* p = eah + (size_t)jb * 8;
        unsigned a0[8], a1[8];
#pragma unroll
        for (int k = 0; k < 8; ++k) { a0[k] = uloadu(p + k); a1[k] = uloadu(p + 8 + k); }
        float m0 = 0.0f, m1 = 0.0f;
#pragma unroll
        for (int k = 0; k < 8; ++k) {
            m0 = dot2acc(a0[k], wh[k], m0);
            m1 = dot2acc(a1[k], wh[k], m1);
        }
        agg += fmaxf(xv + (half ? m1 : m0) + ebv, 0.0f);
    }
    if (j < end) {                     // single tail edge: half 0 contributes
        int jb = __builtin_amdgcn_readfirstlane(j);
        int s0 = uloadi(pidx + jb);
        float xv = (float)xin[(size_t)s0 * 32 + ch];
        const unsigned* p = eah + (size_t)jb * 8;
        float m0 = 0.0f;
#pragma unroll
        for (int k = 0; k < 8; ++k) m0 = dot2acc(uloadu(p + k), wh[k], m0);
        agg += (half == 0) ? fmaxf(xv + m0 + ebv, 0.0f) : 0.0f;
    }
    agg += __shfl_xor(agg, 32);

    float h_in = 0.0f;
    if (lane < 32) h_in = (float)xin[(size_t)node * 32 + lane] + agg;

    float hid = b1[lane];
#pragma unroll
    for (int i = 0; i < 32; ++i)
        hid += __shfl(h_in, i) * w1_lds[i * 64 + lane];
    hid = fmaxf(hid, 0.0f);

    float o = b2[lane];
#pragma unroll
    for (int i = 0; i < 64; ++i)
        o += __shfl(hid, i) * w2[i * 64 + lane];

    hout[(size_t)node * 64 + lane] = (hf)fmaxf(o, 0.0f);
}

// ---------------------------------------------------------------------------
// gine64: R13 form + one-group-ahead gather prefetch (8 gathers in flight).
// Single-variable test of the MLP ceiling in the fp16 latency regime.
// ---------------------------------------------------------------------------
__global__ __launch_bounds__(256) void gine64_kernel(
    const hf* __restrict__ xin, const int* __restrict__ pidx,
    const int* __restrict__ rowptr, const unsigned* __restrict__ eah,
    const float* __restrict__ ew, const float* __restrict__ eb,
    const float* __restrict__ w1, const float* __restrict__ b1,
    const float* __restrict__ w2, const float* __restrict__ b2,
    hf* __restrict__ hout)
{
    __shared__ float w1_lds[64 * 64];
    for (int i = threadIdx.x; i < 64 * 64; i += 256) w1_lds[i] = w1[i];
    __syncthreads();

    int wave = threadIdx.x >> 6, lane = threadIdx.x & 63;
    int node = blockIdx.x * 4 + wave;
    if (node >= NN) return;

    hf2 wh[8];
#pragma unroll
    for (int k = 0; k < 8; ++k) {
        wh[k].x = (_Float16)ew[(2 * k) * 64 + lane];
        wh[k].y = (_Float16)ew[(2 * k + 1) * 64 + lane];
    }
    float ebv = eb[lane];

    int start = rowptr[node], end = rowptr[node + 1];
    float agg = 0.0f;

    int nfull = (end - start) & ~3;
    int jend4 = start + nfull;
    int j = start;
    float xc0, xc1, xc2, xc3;               // prefetched x rows (f32 from hf)
    if (j < jend4) {                         // prologue: group 0
        int jb = __builtin_amdgcn_readfirstlane(j);
        int s0 = uloadi(pidx + jb),     s1 = uloadi(pidx + jb + 1);
        int s2 = uloadi(pidx + jb + 2), s3 = uloadi(pidx + jb + 3);
        xc0 = (float)xin[(size_t)s0 * 64 + lane];
        xc1 = (float)xin[(size_t)s1 * 64 + lane];
        xc2 = (float)xin[(size_t)s2 * 64 + lane];
        xc3 = (float)xin[(size_t)s3 * 64 + lane];
    }
    for (; j < jend4; j += 4) {
        int jb = __builtin_amdgcn_readfirstlane(j);
        bool more = (jb + 4) < jend4;        // uniform
        float xn0, xn1, xn2, xn3;
        if (more) {                          // issue next group's gathers early
            int s0 = uloadi(pidx + jb + 4), s1 = uloadi(pidx + jb + 5);
            int s2 = uloadi(pidx + jb + 6), s3 = uloadi(pidx + jb + 7);
            xn0 = (float)xin[(size_t)s0 * 64 + lane];
            xn1 = (float)xin[(size_t)s1 * 64 + lane];
            xn2 = (float)xin[(size_t)s2 * 64 + lane];
            xn3 = (float)xin[(size_t)s3 * 64 + lane];
        }
        const unsigned* p = eah + (size_t)jb * 8;
        unsigned a0[8], a1[8], a2[8], a3[8];
#pragma unroll
        for (int k = 0; k < 8; ++k) {
            a0[k] = uloadu(p + k);
            a1[k] = uloadu(p + 8 + k);
            a2[k] = uloadu(p + 16 + k);
            a3[k] = uloadu(p + 24 + k);
        }
        float m0 = xc0 + ebv, m1 = xc1 + ebv, m2 = xc2 + ebv, m3 = xc3 + ebv;
#pragma unroll
        for (int k = 0; k < 8; ++k) {
            m0 = dot2acc(a0[k], wh[k], m0);
            m1 = dot2acc(a1[k], wh[k], m1);
            m2 = dot2acc(a2[k], wh[k], m2);
            m3 = dot2acc(a3[k], wh[k], m3);
        }
        agg += fmaxf(m0, 0.0f) + fmaxf(m1, 0.0f)
             + fmaxf(m2, 0.0f) + fmaxf(m3, 0.0f);
        if (more) { xc0 = xn0; xc1 = xn1; xc2 = xn2; xc3 = xn3; }
    }
    for (; j < end; ++j) {                   // tail (<=3 edges)
        int jb = __builtin_amdgcn_readfirstlane(j);
        int s0 = uloadi(pidx + jb);
        float m0 = (float)xin[(size_t)s0 * 64 + lane] + ebv;
        const unsigned* p = eah + (size_t)jb * 8;
#pragma unroll
        for (int k = 0; k < 8; ++k) m0 = dot2acc(uloadu(p + k), wh[k], m0);
        agg += fmaxf(m0, 0.0f);
    }

    float h_in = (float)xin[(size_t)node * 64 + lane] + agg;

    float hid = b1[lane];
#pragma unroll
    for (int i = 0; i < 64; ++i)
        hid += __shfl(h_in, i) * w1_lds[i * 64 + lane];
    hid = fmaxf(hid, 0.0f);

    float o = b2[lane];
#pragma unroll
    for (int i = 0; i < 64; ++i)
        o += __shfl(hid, i) * w2[i * 64 + lane];

    hout[(size_t)node * 64 + lane] = (hf)fmaxf(o, 0.0f);
}

// ---------------------------------------------------------------------------
// Set2Set v3 (fp16 h2): single-sweep online softmax per wave.
// ---------------------------------------------------------------------------
__global__ __launch_bounds__(1024) void set2set_head_v3(
    const hf* __restrict__ h2, const int* __restrict__ brow,
    const float* __restrict__ wihT, const float* __restrict__ whhT,
    const float* __restrict__ bih, const float* __restrict__ bhh,
    const float* __restrict__ dw, const float* __restrict__ db,
    const float* __restrict__ ow, const float* __restrict__ ob,
    float* __restrict__ outp)
{
    int b = blockIdx.x, tid = threadIdx.x;
    int wv = tid >> 6, lane = tid & 63;
    __shared__ float qstar[128], hh[64], cc[64];
    __shared__ float gpart[4][256];
    __shared__ float redw[16][64];
    __shared__ float redm[16], reds[16];

    int start = brow[b], end = brow[b + 1];

    if (tid < 128) qstar[tid] = 0.0f;
    if (tid < 64) { hh[tid] = 0.0f; cc[tid] = 0.0f; }
    __syncthreads();

    for (int step = 0; step < 3; ++step) {
        {
            int p = tid >> 8, g = tid & 255;
            float acc = 0.0f;
            const float* wT = wihT + (size_t)(32 * p) * 256 + g;
#pragma unroll 8
            for (int k = 0; k < 32; ++k) acc += qstar[32 * p + k] * wT[(size_t)k * 256];
            const float* hT = whhT + (size_t)(16 * p) * 256 + g;
#pragma unroll 8
            for (int k = 0; k < 16; ++k) acc += hh[16 * p + k] * hT[(size_t)k * 256];
            gpart[p][g] = acc;
        }
        __syncthreads();
        if (tid < 64) {
            float gi = bih[tid]       + bhh[tid]       + gpart[0][tid]       + gpart[1][tid]       + gpart[2][tid]       + gpart[3][tid];
            float gf = bih[64 + tid]  + bhh[64 + tid]  + gpart[0][64 + tid]  + gpart[1][64 + tid]  + gpart[2][64 + tid]  + gpart[3][64 + tid];
            float gg = bih[128 + tid] + bhh[128 + tid] + gpart[0][128 + tid] + gpart[1][128 + tid] + gpart[2][128 + tid] + gpart[3][128 + tid];
            float go = bih[192 + tid] + bhh[192 + tid] + gpart[0][192 + tid] + gpart[1][192 + tid] + gpart[2][192 + tid] + gpart[3][192 + tid];
            float c = sigmoidf_(gf) * cc[tid] + sigmoidf_(gi) * tanhf(gg);
            cc[tid] = c;
            hh[tid] = sigmoidf_(go) * tanhf(c);
        }
        __syncthreads();

        float qv = hh[lane];
        float mw = -INFINITY, sw = 0.0f, rw = 0.0f;
        for (int n = start + wv; n < end; n += 16) {
            float v = (float)h2[(size_t)n * 64 + lane];
            float p = v * qv;
#pragma unroll
            for (int off = 32; off; off >>= 1) p += __shfl_xor(p, off);
            float nm = fmaxf(mw, p);
            float sc = __expf(mw - nm);
            float pe = __expf(p - nm);
            sw = sw * sc + pe;
            rw = rw * sc + pe * v;
            mw = nm;
        }
        redm[wv] = mw; reds[wv] = sw; redw[wv][lane] = rw;
        __syncthreads();
        if (tid < 64) {
            float M = -INFINITY;
#pragma unroll
            for (int w = 0; w < 16; ++w) M = fmaxf(M, redm[w]);
            float S = 0.0f, R = 0.0f;
#pragma unroll
            for (int w = 0; w < 16; ++w) {
                float mm = redm[w];
                if (mm > -INFINITY) {
                    float sc = __expf(mm - M);
                    S += reds[w] * sc;
                    R += redw[w][tid] * sc;
                }
            }
            qstar[tid] = hh[tid];
            qstar[64 + tid] = (S > 0.0f) ? R / S : 0.0f;
        }
        __syncthreads();
    }

    if (tid < 64) {
        float z = db[tid];
#pragma unroll 4
        for (int k = 0; k < 128; ++k) z += qstar[k] * dw[k * 64 + tid];
        redw[0][tid] = fmaxf(z, 0.0f);
    }
    __syncthreads();
    if (tid < 64) {
        float t = redw[0][tid] * ow[tid];
#pragma unroll
        for (int off = 32; off; off >>= 1) t += __shfl_xor(t, off);
        if (tid == 0) outp[b] = t + ob[0];
    }
}

// ---------------------------------------------------------------------------
extern "C" void kernel_launch(void* const* d_in, const int* in_sizes, int n_in,
                              void* d_out, int out_size, void* d_ws, size_t ws_size,
                              hipStream_t stream)
{
    const float* x     = (const float*)d_in[0];
    const float* eattr = (const float*)d_in[1];
    const float* efeat = (const float*)d_in[2];
    const int*   ei    = (const int*)d_in[3];
    const int*   batch = (const int*)d_in[4];
    const float* c0_ew = (const float*)d_in[5];  const float* c0_eb = (const float*)d_in[6];
    const float* c0_w1 = (const float*)d_in[7];  const float* c0_b1 = (const float*)d_in[8];
    const float* c0_w2 = (const float*)d_in[9];  const float* c0_b2 = (const float*)d_in[10];
    const float* c1_ew = (const float*)d_in[11]; const float* c1_eb = (const float*)d_in[12];
    const float* c1_w1 = (const float*)d_in[13]; const float* c1_b1 = (const float*)d_in[14];
    const float* c1_w2 = (const float*)d_in[15]; const float* c1_b2 = (const float*)d_in[16];
    const float* wih   = (const float*)d_in[17]; const float* bih   = (const float*)d_in[18];
    const float* whh   = (const float*)d_in[19]; const float* bhh   = (const float*)d_in[20];
    const float* dw    = (const float*)d_in[21]; const float* dbias = (const float*)d_in[22];
    const float* ow    = (const float*)d_in[23]; const float* ob    = (const float*)d_in[24];

    float* out = (float*)d_out;
    int* iws = (int*)d_ws;

    // layout (4B words): counts NN | rowptr NN+1 | brow BB+1 | wihT 32768 |
    //   whhT 16384 | srcp EE | xh NN*16 | [align] eah EE*8 | h1h NN*32 |
    //   h2h NN*32.  rnk (EE words) aliases h1h.
    int* counts = iws;
    int* rowptr = counts + NN;
    int* brow   = rowptr + NN + 1;
    size_t off0 = ((size_t)2 * NN + 1 + (BB + 1) + 15) & ~(size_t)15;
    float* wihT = (float*)(iws + off0);
    float* whhT = wihT + 128 * 256;
    int*   srcp = (int*)(whhT + 64 * 256);
    unsigned* xh = (unsigned*)(srcp + EE);
    size_t offE = (off0 + 128 * 256 + 64 * 256 + EE + (size_t)NN * 16 + 15) & ~(size_t)15;
    unsigned* eah = (unsigned*)(iws + offE);
    hf* h1h = (hf*)(eah + (size_t)EE * 8);
    hf* h2h = h1h + (size_t)NN * 64;
    int* rnk = (int*)h1h;

    int setup_grid = (NN * 8 + 255) / 256;
    setup_kernel<<<setup_grid, 256, 0, stream>>>(batch, brow, wih, whh,
                                                 wihT, whhT, counts, x, xh);
    rank_kernel<<<(EE + 255) / 256, 256, 0, stream>>>(ei, counts, rnk);
    scan_kernel<<<1, 1024, 0, stream>>>(counts, rowptr);
    pack_kernel<<<(EE + 255) / 256, 256, 0, stream>>>(
        ei, rnk, rowptr, eattr, efeat, srcp, eah);
    gine32_kernel<<<(NN + 3) / 4, 256, 0, stream>>>(
        (const hf*)xh, srcp, rowptr, eah,
        c0_ew, c0_eb, c0_w1, c0_b1, c0_w2, c0_b2, h1h);
    gine64_kernel<<<(NN + 3) / 4, 256, 0, stream>>>(
        h1h, srcp, rowptr, eah,
        c1_ew, c1_eb, c1_w1, c1_b1, c1_w2, c1_b2, h2h);
    set2set_head_v3<<<BB, 1024, 0, stream>>>(h2h, brow, wihT, whhT, bih, bhh,
                                             dw, dbias, ow, ob, out);
}

// Round 18
// 378.385 us; speedup vs baseline: 1.0301x; 1.0301x over previous
//
#include <hip/hip_runtime.h>
#include <math.h>

#define NN 50000
#define EE 1000000
#define BB 512

typedef _Float16 hf;
typedef __attribute__((ext_vector_type(2))) _Float16 hf2;

__device__ __forceinline__ float sigmoidf_(float x) { return 1.0f / (1.0f + __expf(-x)); }

__device__ __forceinline__ int uloadi(const int* p) {
    return __builtin_amdgcn_readfirstlane(*p);
}
__device__ __forceinline__ unsigned uloadu(const unsigned* p) {
    return (unsigned)__builtin_amdgcn_readfirstlane((int)*p);
}

// f32 pair -> packed half2 (as uint)
__device__ __forceinline__ unsigned pack2(float a, float b) {
    hf2 h; h.x = (_Float16)a; h.y = (_Float16)b;
    return __builtin_bit_cast(unsigned, h);
}

// acc += a(2xf16) . w(2xf16), f32 accumulate
__device__ __forceinline__ float dot2acc(unsigned au, hf2 w, float acc) {
    hf2 a = __builtin_bit_cast(hf2, au);
#if __has_builtin(__builtin_amdgcn_fdot2)
    return __builtin_amdgcn_fdot2(a, w, acc, false);
#else
    return acc + (float)a.x * (float)w.x + (float)a.y * (float)w.y;
#endif
}

// ---------------------------------------------------------------------------
// Fused setup: zero counts + graph bounds + LSTM transpose + x -> fp16.
// ---------------------------------------------------------------------------
__global__ __launch_bounds__(256) void setup_kernel(
    const int* __restrict__ batch, int* __restrict__ brow,
    const float* __restrict__ wih, const float* __restrict__ whh,
    float* __restrict__ wihT, float* __restrict__ whhT,
    int* __restrict__ counts, const float* __restrict__ x, unsigned* __restrict__ xh)
{
    int i = blockIdx.x * 256 + threadIdx.x;
    if (i < NN) {
        counts[i] = 0;
        int bi = batch[i];
        int prev = (i == 0) ? -1 : batch[i - 1];
        for (int v = prev + 1; v <= bi; ++v) brow[v] = i;
        if (i == NN - 1) for (int v = bi + 1; v <= BB; ++v) brow[v] = NN;
    }
    if (i < 128 * 256) wihT[i] = wih[(i & 255) * 128 + (i >> 8)];
    if (i < 64 * 256)  whhT[i] = whh[(i & 255) * 64 + (i >> 8)];
    if (i < NN * 8) {
        float4 v = reinterpret_cast<const float4*>(x)[i];
        uint2 o; o.x = pack2(v.x, v.y); o.y = pack2(v.z, v.w);
        reinterpret_cast<uint2*>(xh)[i] = o;
    }
}

// ---------------------------------------------------------------------------
// CSR build, single atomic pass: rank -> scan -> pack (atomic-free).
// ---------------------------------------------------------------------------
__global__ __launch_bounds__(256) void rank_kernel(const int* __restrict__ ei,
                                                   int* __restrict__ counts,
                                                   int* __restrict__ rnk)
{
    int e = blockIdx.x * 256 + threadIdx.x;
    if (e < EE) rnk[e] = atomicAdd(&counts[ei[EE + e]], 1);
}

__global__ __launch_bounds__(1024) void scan_kernel(const int* __restrict__ counts,
                                                    int* __restrict__ rowptr)
{
    __shared__ int s[1024];
    int t = threadIdx.x;
    const int CH = (NN + 1023) / 1024;
    int lo = t * CH, hi = lo + CH < NN ? lo + CH : NN;
    int sum = 0;
    for (int i = lo; i < hi; ++i) sum += counts[i];
    s[t] = sum;
    __syncthreads();
    for (int off = 1; off < 1024; off <<= 1) {
        int v = (t >= off) ? s[t - off] : 0;
        __syncthreads();
        s[t] += v;
        __syncthreads();
    }
    int base = (t > 0) ? s[t - 1] : 0;
    for (int i = lo; i < hi; ++i) { rowptr[i] = base; base += counts[i]; }
    if (t == 1023) rowptr[NN] = s[1023];
}

__global__ __launch_bounds__(256) void pack_kernel(
    const int* __restrict__ ei, const int* __restrict__ rnk,
    const int* __restrict__ rowptr,
    const float* __restrict__ eattr, const float* __restrict__ efeat,
    int* __restrict__ srcp, unsigned* __restrict__ eah)
{
    int e = blockIdx.x * 256 + threadIdx.x;
    if (e >= EE) return;
    int pos = rowptr[ei[EE + e]] + rnk[e];
    srcp[pos] = ei[e];
    const float4* pa = reinterpret_cast<const float4*>(eattr) + (size_t)e * 2;
    const float4* pf = reinterpret_cast<const float4*>(efeat) + (size_t)e * 2;
    float4 v0 = pa[0], v1 = pa[1], v2 = pf[0], v3 = pf[1];
    uint4 o0, o1;
    o0.x = pack2(v0.x, v0.y); o0.y = pack2(v0.z, v0.w);
    o0.z = pack2(v1.x, v1.y); o0.w = pack2(v1.z, v1.w);
    o1.x = pack2(v2.x, v2.y); o1.y = pack2(v2.z, v2.w);
    o1.z = pack2(v3.x, v3.y); o1.w = pack2(v3.z, v3.w);
    uint4* o = reinterpret_cast<uint4*>(eah + (size_t)pos * 8);
    o[0] = o0; o[1] = o1;
}

// ---------------------------------------------------------------------------
// gine32: one wave/node, one edge per half-wave, 4-edge groups (R16-proven).
// ---------------------------------------------------------------------------
__global__ __launch_bounds__(256) void gine32_kernel(
    const hf* __restrict__ xin, const int* __restrict__ pidx,
    const int* __restrict__ rowptr, const unsigned* __restrict__ eah,
    const float* __restrict__ ew, const float* __restrict__ eb,
    const float* __restrict__ w1, const float* __restrict__ b1,
    const float* __restrict__ w2, const float* __restrict__ b2,
    hf* __restrict__ hout)
{
    __shared__ float w1_lds[32 * 64];
    for (int i = threadIdx.x; i < 32 * 64; i += 256) w1_lds[i] = w1[i];
    __syncthreads();

    int wave = threadIdx.x >> 6, lane = threadIdx.x & 63;
    int node = blockIdx.x * 4 + wave;
    if (node >= NN) return;

    int ch = lane & 31;
    int half = lane >> 5;

    hf2 wh[8];
#pragma unroll
    for (int k = 0; k < 8; ++k) {
        wh[k].x = (_Float16)ew[(2 * k) * 32 + ch];
        wh[k].y = (_Float16)ew[(2 * k + 1) * 32 + ch];
    }
    float ebv = eb[ch];

    int start = rowptr[node], end = rowptr[node + 1];
    float agg = 0.0f;

    int j = start;
    for (; j + 3 < end; j += 4) {      // 4 edges: 2 gather instrs (half-wave each)
        int jb = __builtin_amdgcn_readfirstlane(j);
        int s0 = uloadi(pidx + jb),     s1 = uloadi(pidx + jb + 1);
        int s2 = uloadi(pidx + jb + 2), s3 = uloadi(pidx + jb + 3);
        float xva = (float)xin[(size_t)(half ? s1 : s0) * 32 + ch];
        float xvb = (float)xin[(size_t)(half ? s3 : s2) * 32 + ch];
        const unsigned* p = eah + (size_t)jb * 8;
        unsigned a0[8], a1[8], a2[8], a3[8];
#pragma unroll
        for (int k = 0; k < 8; ++k) {
            a0[k] = uloadu(p + k);
            a1[k] = uloadu(p + 8 + k);
            a2[k] = uloadu(p + 16 + k);
            a3[k] = uloadu(p + 24 + k);
        }
        float m0 = 0.0f, m1 = 0.0f, m2 = 0.0f, m3 = 0.0f;
#pragma unroll
        for (int k = 0; k < 8; ++k) {
            m0 = dot2acc(a0[k], wh[k], m0);
            m1 = dot2acc(a1[k], wh[k], m1);
            m2 = dot2acc(a2[k], wh[k], m2);
            m3 = dot2acc(a3[k], wh[k], m3);
        }
        agg += fmaxf(xva + (half ? m1 : m0) + ebv, 0.0f)
             + fmaxf(xvb + (half ? m3 : m2) + ebv, 0.0f);
    }
    for (; j + 1 < end; j += 2) {      // 2-edge remainder
        int jb = __builtin_amdgcn_readfirstlane(j);
        int s0 = uloadi(pidx + jb);
        int s1 = uloadi(pidx + jb + 1);
        float xv = (float)xin[(size_t)(half ? s1 : s0) * 32 + ch];
        const unsigned* p = eah + (size_t)jb * 8;
        unsigned a0[8], a1[8];
#pragma unroll
        for (int k = 0; k < 8; ++k) { a0[k] = uloadu(p + k); a1[k] = uloadu(p + 8 + k); }
        float m0 = 0.0f, m1 = 0.0f;
#pragma unroll
        for (int k = 0; k < 8; ++k) {
            m0 = dot2acc(a0[k], wh[k], m0);
            m1 = dot2acc(a1[k], wh[k], m1);
        }
        agg += fmaxf(xv + (half ? m1 : m0) + ebv, 0.0f);
    }
    if (j < end) {                     // single tail edge: half 0 contributes
        int jb = __builtin_amdgcn_readfirstlane(j);
        int s0 = uloadi(pidx + jb);
        float xv = (float)xin[(size_t)s0 * 32 + ch];
        const unsigned* p = eah + (size_t)jb * 8;
        float m0 = 0.0f;
#pragma unroll
        for (int k = 0; k < 8; ++k) m0 = dot2acc(uloadu(p + k), wh[k], m0);
        agg += (half == 0) ? fmaxf(xv + m0 + ebv, 0.0f) : 0.0f;
    }
    agg += __shfl_xor(agg, 32);

    float h_in = 0.0f;
    if (lane < 32) h_in = (float)xin[(size_t)node * 32 + lane] + agg;

    float hid = b1[lane];
#pragma unroll
    for (int i = 0; i < 32; ++i)
        hid += __shfl(h_in, i) * w1_lds[i * 64 + lane];
    hid = fmaxf(hid, 0.0f);

    float o = b2[lane];
#pragma unroll
    for (int i = 0; i < 64; ++i)
        o += __shfl(hid, i) * w2[i * 64 + lane];

    hout[(size_t)node * 64 + lane] = (hf)fmaxf(o, 0.0f);
}

// ---------------------------------------------------------------------------
// gine64: exact R13/R16-proven form. 4-edge full-wave groups, scalarized attrs.
// ---------------------------------------------------------------------------
__global__ __launch_bounds__(256) void gine64_kernel(
    const hf* __restrict__ xin, const int* __restrict__ pidx,
    const int* __restrict__ rowptr, const unsigned* __restrict__ eah,
    const float* __restrict__ ew, const float* __restrict__ eb,
    const float* __restrict__ w1, const float* __restrict__ b1,
    const float* __restrict__ w2, const float* __restrict__ b2,
    hf* __restrict__ hout)
{
    __shared__ float w1_lds[64 * 64];
    for (int i = threadIdx.x; i < 64 * 64; i += 256) w1_lds[i] = w1[i];
    __syncthreads();

    int wave = threadIdx.x >> 6, lane = threadIdx.x & 63;
    int node = blockIdx.x * 4 + wave;
    if (node >= NN) return;

    hf2 wh[8];
#pragma unroll
    for (int k = 0; k < 8; ++k) {
        wh[k].x = (_Float16)ew[(2 * k) * 64 + lane];
        wh[k].y = (_Float16)ew[(2 * k + 1) * 64 + lane];
    }
    float ebv = eb[lane];

    int start = rowptr[node], end = rowptr[node + 1];
    float agg = 0.0f;

    int j = start;
    for (; j + 3 < end; j += 4) {
        int jb = __builtin_amdgcn_readfirstlane(j);
        int s0 = uloadi(pidx + jb),     s1 = uloadi(pidx + jb + 1);
        int s2 = uloadi(pidx + jb + 2), s3 = uloadi(pidx + jb + 3);
        float m0 = (float)xin[(size_t)s0 * 64 + lane] + ebv;
        float m1 = (float)xin[(size_t)s1 * 64 + lane] + ebv;
        float m2 = (float)xin[(size_t)s2 * 64 + lane] + ebv;
        float m3 = (float)xin[(size_t)s3 * 64 + lane] + ebv;
        const unsigned* p = eah + (size_t)jb * 8;
        unsigned a0[8], a1[8], a2[8], a3[8];
#pragma unroll
        for (int k = 0; k < 8; ++k) {
            a0[k] = uloadu(p + k);
            a1[k] = uloadu(p + 8 + k);
            a2[k] = uloadu(p + 16 + k);
            a3[k] = uloadu(p + 24 + k);
        }
#pragma unroll
        for (int k = 0; k < 8; ++k) {
            m0 = dot2acc(a0[k], wh[k], m0);
            m1 = dot2acc(a1[k], wh[k], m1);
            m2 = dot2acc(a2[k], wh[k], m2);
            m3 = dot2acc(a3[k], wh[k], m3);
        }
        agg += fmaxf(m0, 0.0f) + fmaxf(m1, 0.0f)
             + fmaxf(m2, 0.0f) + fmaxf(m3, 0.0f);
    }
    for (; j < end; ++j) {
        int jb = __builtin_amdgcn_readfirstlane(j);
        int s0 = uloadi(pidx + jb);
        float m0 = (float)xin[(size_t)s0 * 64 + lane] + ebv;
        const unsigned* p = eah + (size_t)jb * 8;
#pragma unroll
        for (int k = 0; k < 8; ++k) m0 = dot2acc(uloadu(p + k), wh[k], m0);
        agg += fmaxf(m0, 0.0f);
    }

    float h_in = (float)xin[(size_t)node * 64 + lane] + agg;

    float hid = b1[lane];
#pragma unroll
    for (int i = 0; i < 64; ++i)
        hid += __shfl(h_in, i) * w1_lds[i * 64 + lane];
    hid = fmaxf(hid, 0.0f);

    float o = b2[lane];
#pragma unroll
    for (int i = 0; i < 64; ++i)
        o += __shfl(hid, i) * w2[i * 64 + lane];

    hout[(size_t)node * 64 + lane] = (hf)fmaxf(o, 0.0f);
}

// ---------------------------------------------------------------------------
// Set2Set v3 (fp16 h2): single-sweep online softmax per wave.
// ---------------------------------------------------------------------------
__global__ __launch_bounds__(1024) void set2set_head_v3(
    const hf* __restrict__ h2, const int* __restrict__ brow,
    const float* __restrict__ wihT, const float* __restrict__ whhT,
    const float* __restrict__ bih, const float* __restrict__ bhh,
    const float* __restrict__ dw, const float* __restrict__ db,
    const float* __restrict__ ow, const float* __restrict__ ob,
    float* __restrict__ outp)
{
    int b = blockIdx.x, tid = threadIdx.x;
    int wv = tid >> 6, lane = tid & 63;
    __shared__ float qstar[128], hh[64], cc[64];
    __shared__ float gpart[4][256];
    __shared__ float redw[16][64];
    __shared__ float redm[16], reds[16];

    int start = brow[b], end = brow[b + 1];

    if (tid < 128) qstar[tid] = 0.0f;
    if (tid < 64) { hh[tid] = 0.0f; cc[tid] = 0.0f; }
    __syncthreads();

    for (int step = 0; step < 3; ++step) {
        {
            int p = tid >> 8, g = tid & 255;
            float acc = 0.0f;
            const float* wT = wihT + (size_t)(32 * p) * 256 + g;
#pragma unroll 8
            for (int k = 0; k < 32; ++k) acc += qstar[32 * p + k] * wT[(size_t)k * 256];
            const float* hT = whhT + (size_t)(16 * p) * 256 + g;
#pragma unroll 8
            for (int k = 0; k < 16; ++k) acc += hh[16 * p + k] * hT[(size_t)k * 256];
            gpart[p][g] = acc;
        }
        __syncthreads();
        if (tid < 64) {
            float gi = bih[tid]       + bhh[tid]       + gpart[0][tid]       + gpart[1][tid]       + gpart[2][tid]       + gpart[3][tid];
            float gf = bih[64 + tid]  + bhh[64 + tid]  + gpart[0][64 + tid]  + gpart[1][64 + tid]  + gpart[2][64 + tid]  + gpart[3][64 + tid];
            float gg = bih[128 + tid] + bhh[128 + tid] + gpart[0][128 + tid] + gpart[1][128 + tid] + gpart[2][128 + tid] + gpart[3][128 + tid];
            float go = bih[192 + tid] + bhh[192 + tid] + gpart[0][192 + tid] + gpart[1][192 + tid] + gpart[2][192 + tid] + gpart[3][192 + tid];
            float c = sigmoidf_(gf) * cc[tid] + sigmoidf_(gi) * tanhf(gg);
            cc[tid] = c;
            hh[tid] = sigmoidf_(go) * tanhf(c);
        }
        __syncthreads();

        float qv = hh[lane];
        float mw = -INFINITY, sw = 0.0f, rw = 0.0f;
        for (int n = start + wv; n < end; n += 16) {
            float v = (float)h2[(size_t)n * 64 + lane];
            float p = v * qv;
#pragma unroll
            for (int off = 32; off; off >>= 1) p += __shfl_xor(p, off);
            float nm = fmaxf(mw, p);
            float sc = __expf(mw - nm);
            float pe = __expf(p - nm);
            sw = sw * sc + pe;
            rw = rw * sc + pe * v;
            mw = nm;
        }
        redm[wv] = mw; reds[wv] = sw; redw[wv][lane] = rw;
        __syncthreads();
        if (tid < 64) {
            float M = -INFINITY;
#pragma unroll
            for (int w = 0; w < 16; ++w) M = fmaxf(M, redm[w]);
            float S = 0.0f, R = 0.0f;
#pragma unroll
            for (int w = 0; w < 16; ++w) {
                float mm = redm[w];
                if (mm > -INFINITY) {
                    float sc = __expf(mm - M);
                    S += reds[w] * sc;
                    R += redw[w][tid] * sc;
                }
            }
            qstar[tid] = hh[tid];
            qstar[64 + tid] = (S > 0.0f) ? R / S : 0.0f;
        }
        __syncthreads();
    }

    if (tid < 64) {
        float z = db[tid];
#pragma unroll 4
        for (int k = 0; k < 128; ++k) z += qstar[k] * dw[k * 64 + tid];
        redw[0][tid] = fmaxf(z, 0.0f);
    }
    __syncthreads();
    if (tid < 64) {
        float t = redw[0][tid] * ow[tid];
#pragma unroll
        for (int off = 32; off; off >>= 1) t += __shfl_xor(t, off);
        if (tid == 0) outp[b] = t + ob[0];
    }
}

// ---------------------------------------------------------------------------
extern "C" void kernel_launch(void* const* d_in, const int* in_sizes, int n_in,
                              void* d_out, int out_size, void* d_ws, size_t ws_size,
                              hipStream_t stream)
{
    const float* x     = (const float*)d_in[0];
    const float* eattr = (const float*)d_in[1];
    const float* efeat = (const float*)d_in[2];
    const int*   ei    = (const int*)d_in[3];
    const int*   batch = (const int*)d_in[4];
    const float* c0_ew = (const float*)d_in[5];  const float* c0_eb = (const float*)d_in[6];
    const float* c0_w1 = (const float*)d_in[7];  const float* c0_b1 = (const float*)d_in[8];
    const float* c0_w2 = (const float*)d_in[9];  const float* c0_b2 = (const float*)d_in[10];
    const float* c1_ew = (const float*)d_in[11]; const float* c1_eb = (const float*)d_in[12];
    const float* c1_w1 = (const float*)d_in[13]; const float* c1_b1 = (const float*)d_in[14];
    const float* c1_w2 = (const float*)d_in[15]; const float* c1_b2 = (const float*)d_in[16];
    const float* wih   = (const float*)d_in[17]; const float* bih   = (const float*)d_in[18];
    const float* whh   = (const float*)d_in[19]; const float* bhh   = (const float*)d_in[20];
    const float* dw    = (const float*)d_in[21]; const float* dbias = (const float*)d_in[22];
    const float* ow    = (const float*)d_in[23]; const float* ob    = (const float*)d_in[24];

    float* out = (float*)d_out;
    int* iws = (int*)d_ws;

    // layout (4B words): counts NN | rowptr NN+1 | brow BB+1 | wihT 32768 |
    //   whhT 16384 | srcp EE | xh NN*16 | [align] eah EE*8 | h1h NN*32 |
    //   h2h NN*32.  rnk (EE words) aliases h1h.
    int* counts = iws;
    int* rowptr = counts + NN;
    int* brow   = rowptr + NN + 1;
    size_t off0 = ((size_t)2 * NN + 1 + (BB + 1) + 15) & ~(size_t)15;
    float* wihT = (float*)(iws + off0);
    float* whhT = wihT + 128 * 256;
    int*   srcp = (int*)(whhT + 64 * 256);
    unsigned* xh = (unsigned*)(srcp + EE);
    size_t offE = (off0 + 128 * 256 + 64 * 256 + EE + (size_t)NN * 16 + 15) & ~(size_t)15;
    unsigned* eah = (unsigned*)(iws + offE);
    hf* h1h = (hf*)(eah + (size_t)EE * 8);
    hf* h2h = h1h + (size_t)NN * 64;
    int* rnk = (int*)h1h;

    int setup_grid = (NN * 8 + 255) / 256;
    setup_kernel<<<setup_grid, 256, 0, stream>>>(batch, brow, wih, whh,
                                                 wihT, whhT, counts, x, xh);
    rank_kernel<<<(EE + 255) / 256, 256, 0, stream>>>(ei, counts, rnk);
    scan_kernel<<<1, 1024, 0, stream>>>(counts, rowptr);
    pack_kernel<<<(EE + 255) / 256, 256, 0, stream>>>(
        ei, rnk, rowptr, eattr, efeat, srcp, eah);
    gine32_kernel<<<(NN + 3) / 4, 256, 0, stream>>>(
        (const hf*)xh, srcp, rowptr, eah,
        c0_ew, c0_eb, c0_w1, c0_b1, c0_w2, c0_b2, h1h);
    gine64_kernel<<<(NN + 3) / 4, 256, 0, stream>>>(
        h1h, srcp, rowptr, eah,
        c1_ew, c1_eb, c1_w1, c1_b1, c1_w2, c1_b2, h2h);
    set2set_head_v3<<<BB, 1024, 0, stream>>>(h2h, brow, wihT, whhT, bih, bhh,
                                             dw, dbias, ow, ob, out);
}